// Round 9
// baseline (452.069 us; speedup 1.0000x reference)
//
#include <hip/hip_runtime.h>

#define DF 128   // feature dim (D_IN == H == 128)
#define EB 4096  // edges per radix block

typedef float f32x4 __attribute__((ext_vector_type(4)));
typedef _Float16 h16x8 __attribute__((ext_vector_type(8)));

// ---------- radix CSR build (all atomics in LDS) ----------
__global__ __launch_bounds__(256) void p1a_hist(const int* __restrict__ ei, int E,
                                                int NBUKP, int* __restrict__ parthist) {
    __shared__ int hist[512];
    int t = threadIdx.x;
    for (int i = t; i < NBUKP; i += 256) hist[i] = 0;
    __syncthreads();
    int e0 = blockIdx.x * EB;
    #pragma unroll
    for (int j = 0; j < EB / 256; ++j) {
        int e = e0 + j * 256 + t;
        if (e < E) atomicAdd(&hist[ei[E + e] >> 8], 1);
    }
    __syncthreads();
    for (int i = t; i < NBUKP; i += 256)
        parthist[(size_t)blockIdx.x * NBUKP + i] = hist[i];
}

__global__ __launch_bounds__(256) void colscan_kernel(int* __restrict__ parthist,
                                                      int NBLK, int NBUKP,
                                                      int* __restrict__ btotal) {
    __shared__ int wsum[4];
    int k = blockIdx.x;
    int t = threadIdx.x;
    int Q = (NBLK + 255) / 256;
    int b0 = t * Q;
    int local[8];
    int s = 0;
    for (int j = 0; j < Q; ++j) {
        int b = b0 + j;
        int v = (b < NBLK) ? parthist[(size_t)b * NBUKP + k] : 0;
        local[j] = v;
        s += v;
    }
    int lane = t & 63, wid = t >> 6;
    int incl = s;
    #pragma unroll
    for (int off = 1; off < 64; off <<= 1) {
        int n = __shfl_up(incl, off, 64);
        if (lane >= off) incl += n;
    }
    if (lane == 63) wsum[wid] = incl;
    __syncthreads();
    int wbase = 0, total = 0;
    #pragma unroll
    for (int w = 0; w < 4; ++w) {
        int v = wsum[w];
        if (w < wid) wbase += v;
        total += v;
    }
    int run = wbase + incl - s;
    for (int j = 0; j < Q; ++j) {
        int b = b0 + j;
        if (b < NBLK) parthist[(size_t)b * NBUKP + k] = run;
        run += local[j];
    }
    if (t == 0) btotal[k] = total;
}

__global__ __launch_bounds__(1024) void scan_offsets_kernel(int* __restrict__ partials, int NB,
                                                            int* __restrict__ scan_end) {
    __shared__ int wtot[16];
    int t = threadIdx.x, lane = t & 63, wid = t >> 6;
    int c = (t < NB) ? partials[t] : 0;
    int incl = c;
    #pragma unroll
    for (int off = 1; off < 64; off <<= 1) {
        int n = __shfl_up(incl, off, 64);
        if (lane >= off) incl += n;
    }
    if (lane == 63) wtot[wid] = incl;
    __syncthreads();
    int wbase = 0, total = 0;
    #pragma unroll
    for (int w = 0; w < 16; ++w) {
        int v = wtot[w];
        if (w < wid) wbase += v;
        total += v;
    }
    if (t < NB) partials[t] = wbase + incl - c;
    if (t == 0) *scan_end = total;
}

__global__ __launch_bounds__(256) void p1c_scatter(const int* __restrict__ ei, int E,
                                                   int NBUK, int NBUKP,
                                                   const int* __restrict__ parthist,
                                                   const int* __restrict__ bbase,
                                                   unsigned int* __restrict__ pbuf) {
    __shared__ int cur[512];
    int t = threadIdx.x;
    for (int i = t; i < NBUK; i += 256)
        cur[i] = bbase[i] + parthist[(size_t)blockIdx.x * NBUKP + i];
    __syncthreads();
    int e0 = blockIdx.x * EB;
    #pragma unroll
    for (int j = 0; j < EB / 256; ++j) {
        int e = e0 + j * 256 + t;
        if (e < E) {
            int s = ei[e], d = ei[E + e];
            int pos = atomicAdd(&cur[d >> 8], 1);
            pbuf[pos] = ((unsigned)s << 8) | (unsigned)(d & 255);
        }
    }
}

__global__ __launch_bounds__(256) void p2_csr(const unsigned int* __restrict__ pbuf,
                                              const int* __restrict__ bbase,
                                              int N, int E,
                                              int* __restrict__ edges4,
                                              int* __restrict__ row_start,
                                              float* __restrict__ dis) {
    __shared__ int hist[256];
    __shared__ int cur[256];
    __shared__ int wsum[4];
    int k = blockIdx.x, t = threadIdx.x;
    int gbase = bbase[k], gend = bbase[k + 1];
    hist[t] = 0;
    __syncthreads();
    for (int p = gbase + t; p < gend; p += 256)
        atomicAdd(&hist[pbuf[p] & 255], 1);
    __syncthreads();
    int c = hist[t];
    int lane = t & 63, wid = t >> 6;
    int incl = c;
    #pragma unroll
    for (int off = 1; off < 64; off <<= 1) {
        int n = __shfl_up(incl, off, 64);
        if (lane >= off) incl += n;
    }
    if (lane == 63) wsum[wid] = incl;
    __syncthreads();
    int wbase = 0;
    #pragma unroll
    for (int w = 0; w < 4; ++w)
        if (w < wid) wbase += wsum[w];
    int excl = wbase + incl - c;
    int id = k * 256 + t;
    if (id < N) {
        row_start[id] = gbase + excl;
        dis[id] = rsqrtf((float)(c + 1));   // +1 self loop
    }
    if (k == 0 && t == 0) row_start[N] = E;
    cur[t] = gbase + excl;
    __syncthreads();
    for (int p = gbase + t; p < gend; p += 256) {
        unsigned rec = pbuf[p];
        int pos = atomicAdd(&cur[rec & 255], 1);
        edges4[pos] = (int)(rec >> 8);
    }
}

// ---------- x -> fp16 ----------
__global__ __launch_bounds__(256) void x16_kernel(const float* __restrict__ x,
                                                  _Float16* __restrict__ x16, size_t total8) {
    size_t i = (size_t)blockIdx.x * 256 + threadIdx.x;
    if (i >= total8) return;
    const float4* xp = (const float4*)&x[i * 8];
    float4 a = xp[0], b = xp[1];
    h16x8 o;
    o[0] = (_Float16)a.x; o[1] = (_Float16)a.y; o[2] = (_Float16)a.z; o[3] = (_Float16)a.w;
    o[4] = (_Float16)b.x; o[5] = (_Float16)b.y; o[6] = (_Float16)b.z; o[7] = (_Float16)b.w;
    *(h16x8*)&x16[i * 8] = o;
}

// ---------- W fragment prep: fp16 hi + fp16 lo*2048 planes ----------
// tuple t=(s*8+n)*64+lane, slot j holds k = s*32 + 8*(lane>>4) + j, col = n*16 + (lane&15)
__global__ __launch_bounds__(256) void wprep_kernel(const float* __restrict__ Ws,
                                                    _Float16* __restrict__ WHg,
                                                    _Float16* __restrict__ WLg,
                                                    int total) {
    int g = blockIdx.x * 256 + threadIdx.x;
    if (g >= total) return;
    int l = g >> 11;
    int t = g & 2047;
    int s = t >> 9;
    int n = (t >> 6) & 7;
    int lane = t & 63;
    int kb = s * 32 + ((lane >> 4) << 3);
    int c  = n * 16 + (lane & 15);
    const float* W = Ws + (size_t)l * DF * DF;
    h16x8 hi, lo;
    #pragma unroll
    for (int j = 0; j < 8; ++j) {
        float w = W[(kb + j) * DF + c];
        _Float16 wh = (_Float16)w;
        hi[j] = wh;
        lo[j] = (_Float16)((w - (float)wh) * 2048.f);
    }
    *(h16x8*)&WHg[(size_t)g * 8] = hi;
    *(h16x8*)&WLg[(size_t)g * 8] = lo;
}

// ---------- fp16 MFMA GEMM: g_fp16[r] = (A16 @ W)[r] * dis[r] ----------
// A fp16 fed to MFMA directly (no split); W = Wh + Wl/2048 via dual accumulators.
#define GBM 128
__global__ __launch_bounds__(256) void gemm_mfma(const _Float16* __restrict__ A,
                                                 const _Float16* __restrict__ WHg,
                                                 const _Float16* __restrict__ WLg,
                                                 const float* __restrict__ dis,
                                                 _Float16* __restrict__ C,
                                                 int M) {
    int tid  = threadIdx.x;
    int wid  = tid >> 6;
    int lane = tid & 63;
    int l15  = lane & 15;
    int l4   = lane >> 4;
    size_t row0 = (size_t)blockIdx.x * GBM + wid * 32;

    f32x4 acch[2][8], accl[2][8];
    #pragma unroll
    for (int tr = 0; tr < 2; ++tr)
        #pragma unroll
        for (int n = 0; n < 8; ++n) { acch[tr][n] = (f32x4)(0.f); accl[tr][n] = (f32x4)(0.f); }

    const _Float16* Ar0 = A + (row0 + l15) * DF;
    const _Float16* Ar1 = A + (row0 + 16 + l15) * DF;
    bool ok0 = (row0 + l15) < (size_t)M;
    bool ok1 = (row0 + 16 + l15) < (size_t)M;

    #pragma unroll
    for (int s = 0; s < 4; ++s) {
        int c0 = s * 32 + l4 * 8;
        h16x8 a0 = ok0 ? *(const h16x8*)&Ar0[c0] : (h16x8)(_Float16)0;
        h16x8 a1 = ok1 ? *(const h16x8*)&Ar1[c0] : (h16x8)(_Float16)0;
        #pragma unroll
        for (int n = 0; n < 8; ++n) {
            size_t g = (size_t)((s * 8 + n) * 64 + lane) * 8;
            h16x8 bh = *(const h16x8*)&WHg[g];
            h16x8 bl = *(const h16x8*)&WLg[g];
            acch[0][n] = __builtin_amdgcn_mfma_f32_16x16x32_f16(a0, bh, acch[0][n], 0, 0, 0);
            accl[0][n] = __builtin_amdgcn_mfma_f32_16x16x32_f16(a0, bl, accl[0][n], 0, 0, 0);
            acch[1][n] = __builtin_amdgcn_mfma_f32_16x16x32_f16(a1, bh, acch[1][n], 0, 0, 0);
            accl[1][n] = __builtin_amdgcn_mfma_f32_16x16x32_f16(a1, bl, accl[1][n], 0, 0, 0);
        }
    }

    // C/D layout: col = n*16 + l15, row = tr*16 + l4*4 + q
    const float ls = 1.f / 2048.f;
    #pragma unroll
    for (int tr = 0; tr < 2; ++tr) {
        size_t rbase = row0 + tr * 16 + l4 * 4;
        #pragma unroll
        for (int q = 0; q < 4; ++q) {
            size_t r = rbase + q;
            if (r < (size_t)M) {
                float ds = dis[r];
                #pragma unroll
                for (int n = 0; n < 8; ++n)
                    C[r * DF + n * 16 + l15] =
                        (_Float16)((acch[tr][n][q] + accl[tr][n][q] * ls) * ds);
            }
        }
    }
}

// ---------- aggregation: acc = g[i] + sum_e g[src_e]; out = dis*acc + b ----------
// FINAL=0: out fp16 row = fp16(relu(dis*acc + b))  (next layer's GEMM input)
// FINAL=1: out scalar = relu(dis*acc + b) . Wf + bf
template <int FINAL>
__global__ __launch_bounds__(256) void agg_kernel(const _Float16* __restrict__ g,
                                                  const int* __restrict__ edges4,
                                                  const int* __restrict__ row_start,
                                                  const float* __restrict__ dis,
                                                  const float* __restrict__ bias,
                                                  const float* __restrict__ Wf,
                                                  const float* __restrict__ bf,
                                                  void* __restrict__ out, int N) {
    int gid = blockIdx.x * 16 + (threadIdx.x >> 4);  // node
    int l8  = threadIdx.x & 15;                      // 8-feature slot
    if (gid >= N) return;
    const h16x8* gv = (const h16x8*)g;               // 16 per row
    float acc[8];
    {
        h16x8 self = gv[(size_t)gid * 16 + l8];
        #pragma unroll
        for (int j = 0; j < 8; ++j) acc[j] = (float)self[j];
    }
    int s = row_start[gid], e = row_start[gid + 1];
    int p = s;
    for (; p + 4 <= e; p += 4) {
        int s0 = __builtin_nontemporal_load(&edges4[p]);
        int s1 = __builtin_nontemporal_load(&edges4[p + 1]);
        int s2 = __builtin_nontemporal_load(&edges4[p + 2]);
        int s3 = __builtin_nontemporal_load(&edges4[p + 3]);
        h16x8 v0 = gv[(size_t)s0 * 16 + l8];
        h16x8 v1 = gv[(size_t)s1 * 16 + l8];
        h16x8 v2 = gv[(size_t)s2 * 16 + l8];
        h16x8 v3 = gv[(size_t)s3 * 16 + l8];
        #pragma unroll
        for (int j = 0; j < 8; ++j)
            acc[j] += (float)v0[j] + (float)v1[j] + (float)v2[j] + (float)v3[j];
    }
    for (; p < e; ++p) {
        int s0 = __builtin_nontemporal_load(&edges4[p]);
        h16x8 v = gv[(size_t)s0 * 16 + l8];
        #pragma unroll
        for (int j = 0; j < 8; ++j) acc[j] += (float)v[j];
    }
    float d = dis[gid];
    if (FINAL) {
        float pr = 0.f;
        #pragma unroll
        for (int j = 0; j < 8; ++j) {
            float v = fmaxf(acc[j] * d + bias[l8 * 8 + j], 0.f);
            pr += v * Wf[l8 * 8 + j];
        }
        #pragma unroll
        for (int off = 8; off > 0; off >>= 1) pr += __shfl_xor(pr, off, 16);
        if (l8 == 0) ((float*)out)[gid] = pr + bf[0];
    } else {
        h16x8 o;
        #pragma unroll
        for (int j = 0; j < 8; ++j)
            o[j] = (_Float16)fmaxf(acc[j] * d + bias[l8 * 8 + j], 0.f);
        *(h16x8*)&((_Float16*)out)[(size_t)gid * DF + l8 * 8] = o;
    }
}

extern "C" void kernel_launch(void* const* d_in, const int* in_sizes, int n_in,
                              void* d_out, int out_size, void* d_ws, size_t ws_size,
                              hipStream_t stream) {
    const float* x  = (const float*)d_in[0];
    const int*   ei = (const int*)d_in[1];
    const float* Ws = (const float*)d_in[2];
    const float* bs = (const float*)d_in[3];
    const float* Wf = (const float*)d_in[4];
    const float* bf = (const float*)d_in[5];
    float* out = (float*)d_out;

    int N = in_sizes[0] / DF;
    int E = in_sizes[1] / 2;
    int L = in_sizes[2] / (DF * DF);

    int NBUK  = (N + 255) >> 8;
    int NBUKP = NBUK + 1;
    int NBLK  = (E + EB - 1) / EB;

    char* p = (char*)d_ws;
    auto alloc = [&](size_t bytes) {
        char* r = p;
        p += (bytes + 255) & ~(size_t)255;
        return r;
    };
    int*   row_start = (int*)alloc((size_t)(N + 1) * 4);
    float* dis       = (float*)alloc((size_t)N * 4);
    int*   edges4    = (int*)alloc((size_t)E * 4);
    unsigned int* pbuf = (unsigned int*)alloc((size_t)E * 4);
    int*   parthist  = (int*)alloc((size_t)NBLK * NBUKP * 4);
    int*   btotal    = (int*)alloc((size_t)(NBUK + 1) * 4);
    _Float16* bufA16 = (_Float16*)alloc((size_t)N * DF * 2);  // GEMM input (fp16)
    _Float16* bufG   = (_Float16*)alloc((size_t)N * DF * 2);  // g = h*dis (fp16)
    _Float16* WHg    = (_Float16*)alloc((size_t)L * 2048 * 8 * 2);
    _Float16* WLg    = (_Float16*)alloc((size_t)L * 2048 * 8 * 2);

    int WT = L * 2048;
    size_t total8 = (size_t)N * DF / 8;

    wprep_kernel<<<(WT + 255) / 256, 256, 0, stream>>>(Ws, WHg, WLg, WT);
    x16_kernel<<<(int)((total8 + 255) / 256), 256, 0, stream>>>(x, bufA16, total8);
    p1a_hist<<<NBLK, 256, 0, stream>>>(ei, E, NBUKP, parthist);
    colscan_kernel<<<NBUK, 256, 0, stream>>>(parthist, NBLK, NBUKP, btotal);
    scan_offsets_kernel<<<1, 1024, 0, stream>>>(btotal, NBUK, &btotal[NBUK]);
    p1c_scatter<<<NBLK, 256, 0, stream>>>(ei, E, NBUK, NBUKP, parthist, btotal, pbuf);
    p2_csr<<<NBUK, 256, 0, stream>>>(pbuf, btotal, N, E, edges4, row_start, dis);

    for (int l = 0; l < L; ++l) {
        gemm_mfma<<<(N + GBM - 1) / GBM, 256, 0, stream>>>(
            bufA16, WHg + (size_t)l * 16384, WLg + (size_t)l * 16384, dis, bufG, N);
        if (l == L - 1) {
            agg_kernel<1><<<(N + 15) / 16, 256, 0, stream>>>(bufG, edges4, row_start, dis,
                                                             bs + (size_t)l * DF, Wf, bf, out, N);
        } else {
            agg_kernel<0><<<(N + 15) / 16, 256, 0, stream>>>(bufG, edges4, row_start, dis,
                                                             bs + (size_t)l * DF, nullptr, nullptr,
                                                             bufA16, N);
        }
    }
}

// Round 12
// 410.624 us; speedup vs baseline: 1.1009x; 1.1009x over previous
//
#include <hip/hip_runtime.h>

#define DF 128   // feature dim (D_IN == H == 128)
#define EB 4096  // edges per radix block

typedef float f32x4 __attribute__((ext_vector_type(4)));
typedef _Float16 h16x8 __attribute__((ext_vector_type(8)));

// ---------- radix CSR build (all atomics in LDS) ----------
__global__ __launch_bounds__(256) void p1a_hist(const int* __restrict__ ei, int E,
                                                int NBUKP, int* __restrict__ parthist) {
    __shared__ int hist[512];
    int t = threadIdx.x;
    for (int i = t; i < NBUKP; i += 256) hist[i] = 0;
    __syncthreads();
    int e0 = blockIdx.x * EB;
    #pragma unroll
    for (int j = 0; j < EB / 256; ++j) {
        int e = e0 + j * 256 + t;
        if (e < E) atomicAdd(&hist[ei[E + e] >> 8], 1);
    }
    __syncthreads();
    for (int i = t; i < NBUKP; i += 256)
        parthist[(size_t)blockIdx.x * NBUKP + i] = hist[i];
}

__global__ __launch_bounds__(256) void colscan_kernel(int* __restrict__ parthist,
                                                      int NBLK, int NBUKP,
                                                      int* __restrict__ btotal) {
    __shared__ int wsum[4];
    int k = blockIdx.x;
    int t = threadIdx.x;
    int Q = (NBLK + 255) / 256;
    int b0 = t * Q;
    int local[8];
    int s = 0;
    for (int j = 0; j < Q; ++j) {
        int b = b0 + j;
        int v = (b < NBLK) ? parthist[(size_t)b * NBUKP + k] : 0;
        local[j] = v;
        s += v;
    }
    int lane = t & 63, wid = t >> 6;
    int incl = s;
    #pragma unroll
    for (int off = 1; off < 64; off <<= 1) {
        int n = __shfl_up(incl, off, 64);
        if (lane >= off) incl += n;
    }
    if (lane == 63) wsum[wid] = incl;
    __syncthreads();
    int wbase = 0, total = 0;
    #pragma unroll
    for (int w = 0; w < 4; ++w) {
        int v = wsum[w];
        if (w < wid) wbase += v;
        total += v;
    }
    int run = wbase + incl - s;
    for (int j = 0; j < Q; ++j) {
        int b = b0 + j;
        if (b < NBLK) parthist[(size_t)b * NBUKP + k] = run;
        run += local[j];
    }
    if (t == 0) btotal[k] = total;
}

__global__ __launch_bounds__(1024) void scan_offsets_kernel(int* __restrict__ partials, int NB,
                                                            int* __restrict__ scan_end) {
    __shared__ int wtot[16];
    int t = threadIdx.x, lane = t & 63, wid = t >> 6;
    int c = (t < NB) ? partials[t] : 0;
    int incl = c;
    #pragma unroll
    for (int off = 1; off < 64; off <<= 1) {
        int n = __shfl_up(incl, off, 64);
        if (lane >= off) incl += n;
    }
    if (lane == 63) wtot[wid] = incl;
    __syncthreads();
    int wbase = 0, total = 0;
    #pragma unroll
    for (int w = 0; w < 16; ++w) {
        int v = wtot[w];
        if (w < wid) wbase += v;
        total += v;
    }
    if (t < NB) partials[t] = wbase + incl - c;
    if (t == 0) *scan_end = total;
}

__global__ __launch_bounds__(256) void p1c_scatter(const int* __restrict__ ei, int E,
                                                   int NBUK, int NBUKP,
                                                   const int* __restrict__ parthist,
                                                   const int* __restrict__ bbase,
                                                   unsigned int* __restrict__ pbuf) {
    __shared__ int cur[512];
    int t = threadIdx.x;
    for (int i = t; i < NBUK; i += 256)
        cur[i] = bbase[i] + parthist[(size_t)blockIdx.x * NBUKP + i];
    __syncthreads();
    int e0 = blockIdx.x * EB;
    #pragma unroll
    for (int j = 0; j < EB / 256; ++j) {
        int e = e0 + j * 256 + t;
        if (e < E) {
            int s = ei[e], d = ei[E + e];
            int pos = atomicAdd(&cur[d >> 8], 1);
            pbuf[pos] = ((unsigned)s << 8) | (unsigned)(d & 255);
        }
    }
}

__global__ __launch_bounds__(256) void p2_csr(const unsigned int* __restrict__ pbuf,
                                              const int* __restrict__ bbase,
                                              int N, int E,
                                              int* __restrict__ edges4,
                                              int* __restrict__ row_start,
                                              float* __restrict__ dis) {
    __shared__ int hist[256];
    __shared__ int cur[256];
    __shared__ int wsum[4];
    int k = blockIdx.x, t = threadIdx.x;
    int gbase = bbase[k], gend = bbase[k + 1];
    hist[t] = 0;
    __syncthreads();
    for (int p = gbase + t; p < gend; p += 256)
        atomicAdd(&hist[pbuf[p] & 255], 1);
    __syncthreads();
    int c = hist[t];
    int lane = t & 63, wid = t >> 6;
    int incl = c;
    #pragma unroll
    for (int off = 1; off < 64; off <<= 1) {
        int n = __shfl_up(incl, off, 64);
        if (lane >= off) incl += n;
    }
    if (lane == 63) wsum[wid] = incl;
    __syncthreads();
    int wbase = 0;
    #pragma unroll
    for (int w = 0; w < 4; ++w)
        if (w < wid) wbase += wsum[w];
    int excl = wbase + incl - c;
    int id = k * 256 + t;
    if (id < N) {
        row_start[id] = gbase + excl;
        dis[id] = rsqrtf((float)(c + 1));   // +1 self loop
    }
    if (k == 0 && t == 0) row_start[N] = E;
    cur[t] = gbase + excl;
    __syncthreads();
    for (int p = gbase + t; p < gend; p += 256) {
        unsigned rec = pbuf[p];
        int pos = atomicAdd(&cur[rec & 255], 1);
        edges4[pos] = (int)(rec >> 8);
    }
}

// ---------- x -> fp16 ----------
__global__ __launch_bounds__(256) void x16_kernel(const float* __restrict__ x,
                                                  _Float16* __restrict__ x16, size_t total8) {
    size_t i = (size_t)blockIdx.x * 256 + threadIdx.x;
    if (i >= total8) return;
    const float4* xp = (const float4*)&x[i * 8];
    float4 a = xp[0], b = xp[1];
    h16x8 o;
    o[0] = (_Float16)a.x; o[1] = (_Float16)a.y; o[2] = (_Float16)a.z; o[3] = (_Float16)a.w;
    o[4] = (_Float16)b.x; o[5] = (_Float16)b.y; o[6] = (_Float16)b.z; o[7] = (_Float16)b.w;
    *(h16x8*)&x16[i * 8] = o;
}

// ---------- W fragment prep: fp16 hi + fp16 lo*2048 planes ----------
// tuple t=(s*8+n)*64+lane, slot j holds k = s*32 + 8*(lane>>4) + j, col = n*16 + (lane&15)
__global__ __launch_bounds__(256) void wprep_kernel(const float* __restrict__ Ws,
                                                    _Float16* __restrict__ WHg,
                                                    _Float16* __restrict__ WLg,
                                                    int total) {
    int g = blockIdx.x * 256 + threadIdx.x;
    if (g >= total) return;
    int l = g >> 11;
    int t = g & 2047;
    int s = t >> 9;
    int n = (t >> 6) & 7;
    int lane = t & 63;
    int kb = s * 32 + ((lane >> 4) << 3);
    int c  = n * 16 + (lane & 15);
    const float* W = Ws + (size_t)l * DF * DF;
    h16x8 hi, lo;
    #pragma unroll
    for (int j = 0; j < 8; ++j) {
        float w = W[(kb + j) * DF + c];
        _Float16 wh = (_Float16)w;
        hi[j] = wh;
        lo[j] = (_Float16)((w - (float)wh) * 2048.f);
    }
    *(h16x8*)&WHg[(size_t)g * 8] = hi;
    *(h16x8*)&WLg[(size_t)g * 8] = lo;
}

// ---------- fp16 MFMA GEMM, W planes staged in LDS ----------
// g_fp16[r] = (A16 @ (Wh + Wl/2048))[r] * dis[r]
#define GBM 128
__global__ __launch_bounds__(256) void gemm_mfma(const _Float16* __restrict__ A,
                                                 const _Float16* __restrict__ WHg,
                                                 const _Float16* __restrict__ WLg,
                                                 const float* __restrict__ dis,
                                                 _Float16* __restrict__ C,
                                                 int M) {
    __shared__ _Float16 WHs[16384];  // 32 KB
    __shared__ _Float16 WLs[16384];  // 32 KB
    int tid  = threadIdx.x;

    // stage both planes (L2-resident source, 16 B/lane vector copies)
    #pragma unroll
    for (int i = 0; i < 8; ++i) {
        int tpl = tid + i * 256;   // 2048 tuples
        *(h16x8*)&WHs[(size_t)tpl * 8] = *(const h16x8*)&WHg[(size_t)tpl * 8];
        *(h16x8*)&WLs[(size_t)tpl * 8] = *(const h16x8*)&WLg[(size_t)tpl * 8];
    }
    __syncthreads();

    int wid  = tid >> 6;
    int lane = tid & 63;
    int l15  = lane & 15;
    int l4   = lane >> 4;
    size_t row0 = (size_t)blockIdx.x * GBM + wid * 32;

    f32x4 acch[2][8], accl[2][8];
    #pragma unroll
    for (int tr = 0; tr < 2; ++tr)
        #pragma unroll
        for (int n = 0; n < 8; ++n) { acch[tr][n] = (f32x4)(0.f); accl[tr][n] = (f32x4)(0.f); }

    const _Float16* Ar0 = A + (row0 + l15) * DF;
    const _Float16* Ar1 = A + (row0 + 16 + l15) * DF;
    bool ok0 = (row0 + l15) < (size_t)M;
    bool ok1 = (row0 + 16 + l15) < (size_t)M;

    #pragma unroll
    for (int s = 0; s < 4; ++s) {
        int c0 = s * 32 + l4 * 8;
        h16x8 a0 = ok0 ? *(const h16x8*)&Ar0[c0] : (h16x8)(_Float16)0;
        h16x8 a1 = ok1 ? *(const h16x8*)&Ar1[c0] : (h16x8)(_Float16)0;
        #pragma unroll
        for (int n = 0; n < 8; ++n) {
            size_t g = (size_t)((s * 8 + n) * 64 + lane) * 8;
            h16x8 bh = *(const h16x8*)&WHs[g];
            h16x8 bl = *(const h16x8*)&WLs[g];
            acch[0][n] = __builtin_amdgcn_mfma_f32_16x16x32_f16(a0, bh, acch[0][n], 0, 0, 0);
            accl[0][n] = __builtin_amdgcn_mfma_f32_16x16x32_f16(a0, bl, accl[0][n], 0, 0, 0);
            acch[1][n] = __builtin_amdgcn_mfma_f32_16x16x32_f16(a1, bh, acch[1][n], 0, 0, 0);
            accl[1][n] = __builtin_amdgcn_mfma_f32_16x16x32_f16(a1, bl, accl[1][n], 0, 0, 0);
        }
    }

    // C/D layout: col = n*16 + l15, row = tr*16 + l4*4 + q
    const float ls = 1.f / 2048.f;
    #pragma unroll
    for (int tr = 0; tr < 2; ++tr) {
        size_t rbase = row0 + tr * 16 + l4 * 4;
        #pragma unroll
        for (int q = 0; q < 4; ++q) {
            size_t r = rbase + q;
            if (r < (size_t)M) {
                float ds = dis[r];
                #pragma unroll
                for (int n = 0; n < 8; ++n)
                    C[r * DF + n * 16 + l15] =
                        (_Float16)((acch[tr][n][q] + accl[tr][n][q] * ls) * ds);
            }
        }
    }
}

// ---------- aggregation: acc = g[i] + sum_e g[src_e]; out = dis*acc + b ----------
// FINAL=0: out fp16 row = fp16(relu(dis*acc + b))  (next layer's GEMM input)
// FINAL=1: out scalar = relu(dis*acc + b) . Wf + bf
template <int FINAL>
__global__ __launch_bounds__(256) void agg_kernel(const _Float16* __restrict__ g,
                                                  const int* __restrict__ edges4,
                                                  const int* __restrict__ row_start,
                                                  const float* __restrict__ dis,
                                                  const float* __restrict__ bias,
                                                  const float* __restrict__ Wf,
                                                  const float* __restrict__ bf,
                                                  void* __restrict__ out, int N) {
    int gid = blockIdx.x * 16 + (threadIdx.x >> 4);  // node
    int l8  = threadIdx.x & 15;                      // 8-feature slot
    if (gid >= N) return;
    const h16x8* gv = (const h16x8*)g;               // 16 per row
    float acc[8];
    {
        h16x8 self = gv[(size_t)gid * 16 + l8];
        #pragma unroll
        for (int j = 0; j < 8; ++j) acc[j] = (float)self[j];
    }
    int s = row_start[gid], e = row_start[gid + 1];
    int p = s;
    for (; p + 4 <= e; p += 4) {
        int s0 = __builtin_nontemporal_load(&edges4[p]);
        int s1 = __builtin_nontemporal_load(&edges4[p + 1]);
        int s2 = __builtin_nontemporal_load(&edges4[p + 2]);
        int s3 = __builtin_nontemporal_load(&edges4[p + 3]);
        h16x8 v0 = gv[(size_t)s0 * 16 + l8];
        h16x8 v1 = gv[(size_t)s1 * 16 + l8];
        h16x8 v2 = gv[(size_t)s2 * 16 + l8];
        h16x8 v3 = gv[(size_t)s3 * 16 + l8];
        #pragma unroll
        for (int j = 0; j < 8; ++j)
            acc[j] += (float)v0[j] + (float)v1[j] + (float)v2[j] + (float)v3[j];
    }
    for (; p < e; ++p) {
        int s0 = __builtin_nontemporal_load(&edges4[p]);
        h16x8 v = gv[(size_t)s0 * 16 + l8];
        #pragma unroll
        for (int j = 0; j < 8; ++j) acc[j] += (float)v[j];
    }
    float d = dis[gid];
    if (FINAL) {
        float pr = 0.f;
        #pragma unroll
        for (int j = 0; j < 8; ++j) {
            float v = fmaxf(acc[j] * d + bias[l8 * 8 + j], 0.f);
            pr += v * Wf[l8 * 8 + j];
        }
        #pragma unroll
        for (int off = 8; off > 0; off >>= 1) pr += __shfl_xor(pr, off, 16);
        if (l8 == 0) ((float*)out)[gid] = pr + bf[0];
    } else {
        h16x8 o;
        #pragma unroll
        for (int j = 0; j < 8; ++j)
            o[j] = (_Float16)fmaxf(acc[j] * d + bias[l8 * 8 + j], 0.f);
        *(h16x8*)&((_Float16*)out)[(size_t)gid * DF + l8 * 8] = o;
    }
}

extern "C" void kernel_launch(void* const* d_in, const int* in_sizes, int n_in,
                              void* d_out, int out_size, void* d_ws, size_t ws_size,
                              hipStream_t stream) {
    const float* x  = (const float*)d_in[0];
    const int*   ei = (const int*)d_in[1];
    const float* Ws = (const float*)d_in[2];
    const float* bs = (const float*)d_in[3];
    const float* Wf = (const float*)d_in[4];
    const float* bf = (const float*)d_in[5];
    float* out = (float*)d_out;

    int N = in_sizes[0] / DF;
    int E = in_sizes[1] / 2;
    int L = in_sizes[2] / (DF * DF);

    int NBUK  = (N + 255) >> 8;
    int NBUKP = NBUK + 1;
    int NBLK  = (E + EB - 1) / EB;

    char* p = (char*)d_ws;
    auto alloc = [&](size_t bytes) {
        char* r = p;
        p += (bytes + 255) & ~(size_t)255;
        return r;
    };
    int*   row_start = (int*)alloc((size_t)(N + 1) * 4);
    float* dis       = (float*)alloc((size_t)N * 4);
    int*   edges4    = (int*)alloc((size_t)E * 4);
    unsigned int* pbuf = (unsigned int*)alloc((size_t)E * 4);
    int*   parthist  = (int*)alloc((size_t)NBLK * NBUKP * 4);
    int*   btotal    = (int*)alloc((size_t)(NBUK + 1) * 4);
    _Float16* bufA16 = (_Float16*)alloc((size_t)N * DF * 2);  // GEMM input (fp16)
    _Float16* bufG   = (_Float16*)alloc((size_t)N * DF * 2);  // g = h*dis (fp16)
    _Float16* WHg    = (_Float16*)alloc((size_t)L * 2048 * 8 * 2);
    _Float16* WLg    = (_Float16*)alloc((size_t)L * 2048 * 8 * 2);

    int WT = L * 2048;
    size_t total8 = (size_t)N * DF / 8;

    wprep_kernel<<<(WT + 255) / 256, 256, 0, stream>>>(Ws, WHg, WLg, WT);
    x16_kernel<<<(int)((total8 + 255) / 256), 256, 0, stream>>>(x, bufA16, total8);
    p1a_hist<<<NBLK, 256, 0, stream>>>(ei, E, NBUKP, parthist);
    colscan_kernel<<<NBUK, 256, 0, stream>>>(parthist, NBLK, NBUKP, btotal);
    scan_offsets_kernel<<<1, 1024, 0, stream>>>(btotal, NBUK, &btotal[NBUK]);
    p1c_scatter<<<NBLK, 256, 0, stream>>>(ei, E, NBUK, NBUKP, parthist, btotal, pbuf);
    p2_csr<<<NBUK, 256, 0, stream>>>(pbuf, btotal, N, E, edges4, row_start, dis);

    for (int l = 0; l < L; ++l) {
        gemm_mfma<<<(N + GBM - 1) / GBM, 256, 0, stream>>>(
            bufA16, WHg + (size_t)l * 16384, WLg + (size_t)l * 16384, dis, bufG, N);
        if (l == L - 1) {
            agg_kernel<1><<<(N + 15) / 16, 256, 0, stream>>>(bufG, edges4, row_start, dis,
                                                             bs + (size_t)l * DF, Wf, bf, out, N);
        } else {
            agg_kernel<0><<<(N + 15) / 16, 256, 0, stream>>>(bufG, edges4, row_start, dis,
                                                             bs + (size_t)l * DF, nullptr, nullptr,
                                                             bufA16, N);
        }
    }
}

// Round 15
// 391.356 us; speedup vs baseline: 1.1551x; 1.0492x over previous
//
#include <hip/hip_runtime.h>

#define DF 128   // feature dim (D_IN == H == 128)
#define EB 4096  // edges per radix block

typedef float f32x4 __attribute__((ext_vector_type(4)));
typedef _Float16 h16x8 __attribute__((ext_vector_type(8)));

// ---------- radix CSR build (all atomics in LDS) ----------
__global__ __launch_bounds__(256) void p1a_hist(const int* __restrict__ ei, int E,
                                                int NBUKP, int* __restrict__ parthist) {
    __shared__ int hist[512];
    int t = threadIdx.x;
    for (int i = t; i < NBUKP; i += 256) hist[i] = 0;
    __syncthreads();
    int e0 = blockIdx.x * EB;
    #pragma unroll
    for (int j = 0; j < EB / 256; ++j) {
        int e = e0 + j * 256 + t;
        if (e < E) atomicAdd(&hist[ei[E + e] >> 8], 1);
    }
    __syncthreads();
    for (int i = t; i < NBUKP; i += 256)
        parthist[(size_t)blockIdx.x * NBUKP + i] = hist[i];
}

__global__ __launch_bounds__(256) void colscan_kernel(int* __restrict__ parthist,
                                                      int NBLK, int NBUKP,
                                                      int* __restrict__ btotal) {
    __shared__ int wsum[4];
    int k = blockIdx.x;
    int t = threadIdx.x;
    int Q = (NBLK + 255) / 256;
    int b0 = t * Q;
    int local[8];
    int s = 0;
    for (int j = 0; j < Q; ++j) {
        int b = b0 + j;
        int v = (b < NBLK) ? parthist[(size_t)b * NBUKP + k] : 0;
        local[j] = v;
        s += v;
    }
    int lane = t & 63, wid = t >> 6;
    int incl = s;
    #pragma unroll
    for (int off = 1; off < 64; off <<= 1) {
        int n = __shfl_up(incl, off, 64);
        if (lane >= off) incl += n;
    }
    if (lane == 63) wsum[wid] = incl;
    __syncthreads();
    int wbase = 0, total = 0;
    #pragma unroll
    for (int w = 0; w < 4; ++w) {
        int v = wsum[w];
        if (w < wid) wbase += v;
        total += v;
    }
    int run = wbase + incl - s;
    for (int j = 0; j < Q; ++j) {
        int b = b0 + j;
        if (b < NBLK) parthist[(size_t)b * NBUKP + k] = run;
        run += local[j];
    }
    if (t == 0) btotal[k] = total;
}

__global__ __launch_bounds__(1024) void scan_offsets_kernel(int* __restrict__ partials, int NB,
                                                            int* __restrict__ scan_end) {
    __shared__ int wtot[16];
    int t = threadIdx.x, lane = t & 63, wid = t >> 6;
    int c = (t < NB) ? partials[t] : 0;
    int incl = c;
    #pragma unroll
    for (int off = 1; off < 64; off <<= 1) {
        int n = __shfl_up(incl, off, 64);
        if (lane >= off) incl += n;
    }
    if (lane == 63) wtot[wid] = incl;
    __syncthreads();
    int wbase = 0, total = 0;
    #pragma unroll
    for (int w = 0; w < 16; ++w) {
        int v = wtot[w];
        if (w < wid) wbase += v;
        total += v;
    }
    if (t < NB) partials[t] = wbase + incl - c;
    if (t == 0) *scan_end = total;
}

__global__ __launch_bounds__(256) void p1c_scatter(const int* __restrict__ ei, int E,
                                                   int NBUK, int NBUKP,
                                                   const int* __restrict__ parthist,
                                                   const int* __restrict__ bbase,
                                                   unsigned int* __restrict__ pbuf) {
    __shared__ int cur[512];
    int t = threadIdx.x;
    for (int i = t; i < NBUK; i += 256)
        cur[i] = bbase[i] + parthist[(size_t)blockIdx.x * NBUKP + i];
    __syncthreads();
    int e0 = blockIdx.x * EB;
    #pragma unroll
    for (int j = 0; j < EB / 256; ++j) {
        int e = e0 + j * 256 + t;
        if (e < E) {
            int s = ei[e], d = ei[E + e];
            int pos = atomicAdd(&cur[d >> 8], 1);
            pbuf[pos] = ((unsigned)s << 8) | (unsigned)(d & 255);
        }
    }
}

__global__ __launch_bounds__(256) void p2_csr(const unsigned int* __restrict__ pbuf,
                                              const int* __restrict__ bbase,
                                              int N, int E,
                                              int* __restrict__ edges4,
                                              int* __restrict__ row_start,
                                              float* __restrict__ dis) {
    __shared__ int hist[256];
    __shared__ int cur[256];
    __shared__ int wsum[4];
    int k = blockIdx.x, t = threadIdx.x;
    int gbase = bbase[k], gend = bbase[k + 1];
    hist[t] = 0;
    __syncthreads();
    for (int p = gbase + t; p < gend; p += 256)
        atomicAdd(&hist[pbuf[p] & 255], 1);
    __syncthreads();
    int c = hist[t];
    int lane = t & 63, wid = t >> 6;
    int incl = c;
    #pragma unroll
    for (int off = 1; off < 64; off <<= 1) {
        int n = __shfl_up(incl, off, 64);
        if (lane >= off) incl += n;
    }
    if (lane == 63) wsum[wid] = incl;
    __syncthreads();
    int wbase = 0;
    #pragma unroll
    for (int w = 0; w < 4; ++w)
        if (w < wid) wbase += wsum[w];
    int excl = wbase + incl - c;
    int id = k * 256 + t;
    if (id < N) {
        row_start[id] = gbase + excl;
        dis[id] = rsqrtf((float)(c + 1));   // +1 self loop
    }
    if (k == 0 && t == 0) row_start[N] = E;
    cur[t] = gbase + excl;
    __syncthreads();
    for (int p = gbase + t; p < gend; p += 256) {
        unsigned rec = pbuf[p];
        int pos = atomicAdd(&cur[rec & 255], 1);
        edges4[pos] = (int)(rec >> 8);
    }
}

// ---------- x -> fp16 ----------
__global__ __launch_bounds__(256) void x16_kernel(const float* __restrict__ x,
                                                  _Float16* __restrict__ x16, size_t total8) {
    size_t i = (size_t)blockIdx.x * 256 + threadIdx.x;
    if (i >= total8) return;
    const float4* xp = (const float4*)&x[i * 8];
    float4 a = xp[0], b = xp[1];
    h16x8 o;
    o[0] = (_Float16)a.x; o[1] = (_Float16)a.y; o[2] = (_Float16)a.z; o[3] = (_Float16)a.w;
    o[4] = (_Float16)b.x; o[5] = (_Float16)b.y; o[6] = (_Float16)b.z; o[7] = (_Float16)b.w;
    __builtin_nontemporal_store(o, (h16x8*)&x16[i * 8]);
}

// ---------- W fragment prep: fp16 plane ----------
// tuple t=(s*8+n)*64+lane, slot j holds k = s*32 + 8*(lane>>4) + j, col = n*16 + (lane&15)
__global__ __launch_bounds__(256) void wprep_kernel(const float* __restrict__ Ws,
                                                    _Float16* __restrict__ WHg,
                                                    int total) {
    int g = blockIdx.x * 256 + threadIdx.x;
    if (g >= total) return;
    int l = g >> 11;
    int t = g & 2047;
    int s = t >> 9;
    int n = (t >> 6) & 7;
    int lane = t & 63;
    int kb = s * 32 + ((lane >> 4) << 3);
    int c  = n * 16 + (lane & 15);
    const float* W = Ws + (size_t)l * DF * DF;
    h16x8 hi;
    #pragma unroll
    for (int j = 0; j < 8; ++j)
        hi[j] = (_Float16)W[(kb + j) * DF + c];
    *(h16x8*)&WHg[(size_t)g * 8] = hi;
}

// ---------- fp16 MFMA GEMM, W plane staged in LDS (32 KB -> 4 blocks/CU) ----------
// g_fp16[r] = (A16 @ W16)[r] * dis[r]
#define GBM 128
__global__ __launch_bounds__(256) void gemm_mfma(const _Float16* __restrict__ A,
                                                 const _Float16* __restrict__ WHg,
                                                 const float* __restrict__ dis,
                                                 _Float16* __restrict__ C,
                                                 int M) {
    __shared__ _Float16 WHs[16384];  // 32 KB
    int tid  = threadIdx.x;

    // stage plane (L2-resident source, 16 B/lane vector copies)
    #pragma unroll
    for (int i = 0; i < 8; ++i) {
        int tpl = tid + i * 256;   // 2048 tuples
        *(h16x8*)&WHs[(size_t)tpl * 8] = *(const h16x8*)&WHg[(size_t)tpl * 8];
    }
    __syncthreads();

    int wid  = tid >> 6;
    int lane = tid & 63;
    int l15  = lane & 15;
    int l4   = lane >> 4;
    size_t row0 = (size_t)blockIdx.x * GBM + wid * 32;

    f32x4 acc[2][8];
    #pragma unroll
    for (int tr = 0; tr < 2; ++tr)
        #pragma unroll
        for (int n = 0; n < 8; ++n) acc[tr][n] = (f32x4)(0.f);

    const _Float16* Ar0 = A + (row0 + l15) * DF;
    const _Float16* Ar1 = A + (row0 + 16 + l15) * DF;
    bool ok0 = (row0 + l15) < (size_t)M;
    bool ok1 = (row0 + 16 + l15) < (size_t)M;

    #pragma unroll
    for (int s = 0; s < 4; ++s) {
        int c0 = s * 32 + l4 * 8;
        h16x8 a0 = ok0 ? *(const h16x8*)&Ar0[c0] : (h16x8)(_Float16)0;
        h16x8 a1 = ok1 ? *(const h16x8*)&Ar1[c0] : (h16x8)(_Float16)0;
        #pragma unroll
        for (int n = 0; n < 8; ++n) {
            size_t g = (size_t)((s * 8 + n) * 64 + lane) * 8;
            h16x8 bh = *(const h16x8*)&WHs[g];
            acc[0][n] = __builtin_amdgcn_mfma_f32_16x16x32_f16(a0, bh, acc[0][n], 0, 0, 0);
            acc[1][n] = __builtin_amdgcn_mfma_f32_16x16x32_f16(a1, bh, acc[1][n], 0, 0, 0);
        }
    }

    // C/D layout: col = n*16 + l15, row = tr*16 + l4*4 + q
    #pragma unroll
    for (int tr = 0; tr < 2; ++tr) {
        size_t rbase = row0 + tr * 16 + l4 * 4;
        #pragma unroll
        for (int q = 0; q < 4; ++q) {
            size_t r = rbase + q;
            if (r < (size_t)M) {
                float ds = dis[r];
                #pragma unroll
                for (int n = 0; n < 8; ++n)
                    C[r * DF + n * 16 + l15] = (_Float16)(acc[tr][n][q] * ds);
            }
        }
    }
}

// ---------- aggregation: acc = g[i] + sum_e g[src_e]; out = dis*acc + b ----------
// FINAL=0: out fp16 row = fp16(relu(dis*acc + b))  (next layer's GEMM input, NT store)
// FINAL=1: out scalar = relu(dis*acc + b) . Wf + bf
template <int FINAL>
__global__ __launch_bounds__(256) void agg_kernel(const _Float16* __restrict__ g,
                                                  const int* __restrict__ edges4,
                                                  const int* __restrict__ row_start,
                                                  const float* __restrict__ dis,
                                                  const float* __restrict__ bias,
                                                  const float* __restrict__ Wf,
                                                  const float* __restrict__ bf,
                                                  void* __restrict__ out, int N) {
    int gid = blockIdx.x * 16 + (threadIdx.x >> 4);  // node
    int l8  = threadIdx.x & 15;                      // 8-feature slot
    if (gid >= N) return;
    const h16x8* gv = (const h16x8*)g;               // 16 per row
    float acc[8];
    {
        h16x8 self = gv[(size_t)gid * 16 + l8];
        #pragma unroll
        for (int j = 0; j < 8; ++j) acc[j] = (float)self[j];
    }
    int s = row_start[gid], e = row_start[gid + 1];
    int p = s;
    for (; p + 4 <= e; p += 4) {
        int s0 = __builtin_nontemporal_load(&edges4[p]);
        int s1 = __builtin_nontemporal_load(&edges4[p + 1]);
        int s2 = __builtin_nontemporal_load(&edges4[p + 2]);
        int s3 = __builtin_nontemporal_load(&edges4[p + 3]);
        h16x8 v0 = gv[(size_t)s0 * 16 + l8];
        h16x8 v1 = gv[(size_t)s1 * 16 + l8];
        h16x8 v2 = gv[(size_t)s2 * 16 + l8];
        h16x8 v3 = gv[(size_t)s3 * 16 + l8];
        #pragma unroll
        for (int j = 0; j < 8; ++j)
            acc[j] += (float)v0[j] + (float)v1[j] + (float)v2[j] + (float)v3[j];
    }
    for (; p < e; ++p) {
        int s0 = __builtin_nontemporal_load(&edges4[p]);
        h16x8 v = gv[(size_t)s0 * 16 + l8];
        #pragma unroll
        for (int j = 0; j < 8; ++j) acc[j] += (float)v[j];
    }
    float d = dis[gid];
    if (FINAL) {
        float pr = 0.f;
        #pragma unroll
        for (int j = 0; j < 8; ++j) {
            float v = fmaxf(acc[j] * d + bias[l8 * 8 + j], 0.f);
            pr += v * Wf[l8 * 8 + j];
        }
        #pragma unroll
        for (int off = 8; off > 0; off >>= 1) pr += __shfl_xor(pr, off, 16);
        if (l8 == 0) __builtin_nontemporal_store(pr + bf[0], &((float*)out)[gid]);
    } else {
        h16x8 o;
        #pragma unroll
        for (int j = 0; j < 8; ++j)
            o[j] = (_Float16)fmaxf(acc[j] * d + bias[l8 * 8 + j], 0.f);
        __builtin_nontemporal_store(o, (h16x8*)&((_Float16*)out)[(size_t)gid * DF + l8 * 8]);
    }
}

extern "C" void kernel_launch(void* const* d_in, const int* in_sizes, int n_in,
                              void* d_out, int out_size, void* d_ws, size_t ws_size,
                              hipStream_t stream) {
    const float* x  = (const float*)d_in[0];
    const int*   ei = (const int*)d_in[1];
    const float* Ws = (const float*)d_in[2];
    const float* bs = (const float*)d_in[3];
    const float* Wf = (const float*)d_in[4];
    const float* bf = (const float*)d_in[5];
    float* out = (float*)d_out;

    int N = in_sizes[0] / DF;
    int E = in_sizes[1] / 2;
    int L = in_sizes[2] / (DF * DF);

    int NBUK  = (N + 255) >> 8;
    int NBUKP = NBUK + 1;
    int NBLK  = (E + EB - 1) / EB;

    char* p = (char*)d_ws;
    auto alloc = [&](size_t bytes) {
        char* r = p;
        p += (bytes + 255) & ~(size_t)255;
        return r;
    };
    int*   row_start = (int*)alloc((size_t)(N + 1) * 4);
    float* dis       = (float*)alloc((size_t)N * 4);
    int*   edges4    = (int*)alloc((size_t)E * 4);
    unsigned int* pbuf = (unsigned int*)alloc((size_t)E * 4);
    int*   parthist  = (int*)alloc((size_t)NBLK * NBUKP * 4);
    int*   btotal    = (int*)alloc((size_t)(NBUK + 1) * 4);
    _Float16* bufA16 = (_Float16*)alloc((size_t)N * DF * 2);  // GEMM input (fp16)
    _Float16* bufG   = (_Float16*)alloc((size_t)N * DF * 2);  // g = h*dis (fp16)
    _Float16* WHg    = (_Float16*)alloc((size_t)L * 2048 * 8 * 2);

    int WT = L * 2048;
    size_t total8 = (size_t)N * DF / 8;

    wprep_kernel<<<(WT + 255) / 256, 256, 0, stream>>>(Ws, WHg, WT);
    x16_kernel<<<(int)((total8 + 255) / 256), 256, 0, stream>>>(x, bufA16, total8);
    p1a_hist<<<NBLK, 256, 0, stream>>>(ei, E, NBUKP, parthist);
    colscan_kernel<<<NBUK, 256, 0, stream>>>(parthist, NBLK, NBUKP, btotal);
    scan_offsets_kernel<<<1, 1024, 0, stream>>>(btotal, NBUK, &btotal[NBUK]);
    p1c_scatter<<<NBLK, 256, 0, stream>>>(ei, E, NBUK, NBUKP, parthist, btotal, pbuf);
    p2_csr<<<NBUK, 256, 0, stream>>>(pbuf, btotal, N, E, edges4, row_start, dis);

    for (int l = 0; l < L; ++l) {
        gemm_mfma<<<(N + GBM - 1) / GBM, 256, 0, stream>>>(
            bufA16, WHg + (size_t)l * 16384, dis, bufG, N);
        if (l == L - 1) {
            agg_kernel<1><<<(N + 15) / 16, 256, 0, stream>>>(bufG, edges4, row_start, dis,
                                                             bs + (size_t)l * DF, Wf, bf, out, N);
        } else {
            agg_kernel<0><<<(N + 15) / 16, 256, 0, stream>>>(bufG, edges4, row_start, dis,
                                                             bs + (size_t)l * DF, nullptr, nullptr,
                                                             bufA16, N);
        }
    }
}